// Round 1
// baseline (987.027 us; speedup 1.0000x reference)
//
#include <hip/hip_runtime.h>
#include <hip/hip_bf16.h>

// ---------------- graph preprocessing kernels ----------------

__global__ void hist_k(const int* __restrict__ dst, int* __restrict__ deg, int nE) {
    int e = blockIdx.x * 256 + threadIdx.x;
    if (e < nE) atomicAdd(&deg[dst[e]], 1);
}

__global__ void dinv_k(const int* __restrict__ deg, float* __restrict__ dinv, int n) {
    int i = blockIdx.x * 256 + threadIdx.x;
    if (i < n) dinv[i] = rsqrtf((float)deg[i] + 1.0f);
}

// two-level inclusive scan over deg -> exclusive rowptr
__global__ void scan_block_k(const int* __restrict__ deg, int* __restrict__ scanned,
                             int* __restrict__ bsums, int n) {
    __shared__ int s[1024];
    int i = blockIdx.x * 1024 + threadIdx.x;
    int v = (i < n) ? deg[i] : 0;
    s[threadIdx.x] = v;
    __syncthreads();
    for (int off = 1; off < 1024; off <<= 1) {
        int t = (threadIdx.x >= off) ? s[threadIdx.x - off] : 0;
        __syncthreads();
        s[threadIdx.x] += t;
        __syncthreads();
    }
    if (i < n) scanned[i] = s[threadIdx.x];
    if (threadIdx.x == 1023) bsums[blockIdx.x] = s[1023];
}

__global__ void scan_sums_k(int* __restrict__ bsums, int nb) {
    if (threadIdx.x == 0 && blockIdx.x == 0) {
        int acc = 0;
        for (int i = 0; i < nb; ++i) { int v = bsums[i]; bsums[i] = acc; acc += v; }
    }
}

__global__ void scan_final_k(const int* __restrict__ scanned, const int* __restrict__ deg,
                             const int* __restrict__ bsums, int* __restrict__ rowptr,
                             int n, int nE) {
    int i = blockIdx.x * 256 + threadIdx.x;
    if (i < n) rowptr[i] = scanned[i] - deg[i] + bsums[i >> 10];
    if (i == 0) rowptr[n] = nE;
}

__global__ void csr_fill_k(const int* __restrict__ src, const int* __restrict__ dst,
                           const int* __restrict__ rowptr, int* __restrict__ fill,
                           const float* __restrict__ dinv, int* __restrict__ eidx,
                           float* __restrict__ ecoef, int nE) {
    int e = blockIdx.x * 256 + threadIdx.x;
    if (e >= nE) return;
    int d = dst[e], s = src[e];
    int p = rowptr[d] + atomicAdd(&fill[d], 1);
    eidx[p] = s;
    ecoef[p] = dinv[s] * dinv[d];
}

// ---------------- fp32 tiled GEMM: C[M,N] = A[M,K] @ B(,opt ^T) + bias, opt relu ----------------
// BM=BN=64, BK=16, 256 threads, 4x4 per thread. Requires K % 16 == 0.

template <bool TRANSB, bool BIAS, bool RELU>
__global__ __launch_bounds__(256) void gemm_f32(
    const float* __restrict__ A, const float* __restrict__ B,
    const float* __restrict__ bias, float* __restrict__ C,
    int M, int N, int K) {
    __shared__ float As[16][68];
    __shared__ float Bs[16][68];
    const int tid = threadIdx.x;
    const int bm = blockIdx.x * 64;
    const int bn = blockIdx.y * 64;
    const int tm = (tid >> 4) << 2;
    const int tn = (tid & 15) << 2;
    const int arow = tid >> 2;          // 0..63
    const int acol = (tid & 3) << 2;    // 0,4,8,12

    float acc[4][4] = {};

    for (int k0 = 0; k0 < K; k0 += 16) {
        // A tile load (64x16), float4 per thread
        float4 av = make_float4(0.f, 0.f, 0.f, 0.f);
        if (bm + arow < M) av = *(const float4*)&A[(size_t)(bm + arow) * K + k0 + acol];
        As[acol + 0][arow] = av.x; As[acol + 1][arow] = av.y;
        As[acol + 2][arow] = av.z; As[acol + 3][arow] = av.w;

        if constexpr (!TRANSB) {
            const int bk = tid >> 4;          // 0..15
            const int bnn = (tid & 15) << 2;  // 0..60
            float4 bv = make_float4(0.f, 0.f, 0.f, 0.f);
            if (bn + bnn + 3 < N) {
                bv = *(const float4*)&B[(size_t)(k0 + bk) * N + bn + bnn];
            } else {
                float t[4] = {0.f, 0.f, 0.f, 0.f};
                for (int j = 0; j < 4; ++j)
                    if (bn + bnn + j < N) t[j] = B[(size_t)(k0 + bk) * N + bn + bnn + j];
                bv = make_float4(t[0], t[1], t[2], t[3]);
            }
            Bs[bk][bnn + 0] = bv.x; Bs[bk][bnn + 1] = bv.y;
            Bs[bk][bnn + 2] = bv.z; Bs[bk][bnn + 3] = bv.w;
        } else {
            // B is [N][K] row-major; Bs[k][n] = B[bn+n][k0+k]
            const int bnn = tid >> 2;         // 0..63
            const int bk = (tid & 3) << 2;    // 0,4,8,12
            float4 bv = make_float4(0.f, 0.f, 0.f, 0.f);
            if (bn + bnn < N) bv = *(const float4*)&B[(size_t)(bn + bnn) * K + k0 + bk];
            Bs[bk + 0][bnn] = bv.x; Bs[bk + 1][bnn] = bv.y;
            Bs[bk + 2][bnn] = bv.z; Bs[bk + 3][bnn] = bv.w;
        }
        __syncthreads();

#pragma unroll
        for (int k = 0; k < 16; ++k) {
            float a[4], b[4];
#pragma unroll
            for (int i = 0; i < 4; ++i) a[i] = As[k][tm + i];
#pragma unroll
            for (int j = 0; j < 4; ++j) b[j] = Bs[k][tn + j];
#pragma unroll
            for (int i = 0; i < 4; ++i)
#pragma unroll
                for (int j = 0; j < 4; ++j)
                    acc[i][j] = fmaf(a[i], b[j], acc[i][j]);
        }
        __syncthreads();
    }

    for (int i = 0; i < 4; ++i) {
        int row = bm + tm + i;
        if (row >= M) continue;
        for (int j = 0; j < 4; ++j) {
            int col = bn + tn + j;
            if (col >= N) continue;
            float v = acc[i][j];
            if constexpr (BIAS) v += bias[col];
            if constexpr (RELU) v = fmaxf(v, 0.f);
            C[(size_t)row * N + col] = v;
        }
    }
}

// ---------------- GCN aggregation: out[i] = b + dinv2[i]*xw[i] + sum_j coef*xw[src_j] ----------------
// one wave per node, lane handles 4 consecutive features

__global__ __launch_bounds__(256) void agg_k(
    const float* __restrict__ xw, const int* __restrict__ rowptr,
    const int* __restrict__ eidx, const float* __restrict__ ecoef,
    const float* __restrict__ dinv, const float* __restrict__ bias,
    float* __restrict__ out, int n, int N) {
    int wave = threadIdx.x >> 6, lane = threadIdx.x & 63;
    int node = blockIdx.x * 4 + wave;
    if (node >= n) return;
    int nv = N >> 2;
    if (lane >= nv) return;
    const float4* xv = (const float4*)xw;
    float4* ov = (float4*)out;
    float di = dinv[node];
    float s = di * di;
    float4 b4 = ((const float4*)bias)[lane];
    float4 a = xv[(size_t)node * nv + lane];
    float4 acc;
    acc.x = b4.x + s * a.x;
    acc.y = b4.y + s * a.y;
    acc.z = b4.z + s * a.z;
    acc.w = b4.w + s * a.w;
    int beg = rowptr[node], end = rowptr[node + 1];
    for (int e = beg; e < end; ++e) {
        int sn = eidx[e];
        float c = ecoef[e];
        float4 v = xv[(size_t)sn * nv + lane];
        acc.x = fmaf(c, v.x, acc.x);
        acc.y = fmaf(c, v.y, acc.y);
        acc.z = fmaf(c, v.z, acc.z);
        acc.w = fmaf(c, v.w, acc.w);
    }
    ov[(size_t)node * nv + lane] = acc;
}

// ---------------- launcher ----------------

extern "C" void kernel_launch(void* const* d_in, const int* in_sizes, int n_in,
                              void* d_out, int out_size, void* d_ws, size_t ws_size,
                              hipStream_t stream) {
    const float* nodes  = (const float*)d_in[0];
    const int*   edges  = (const int*)d_in[1];
    const float* labelm = (const float*)d_in[2];
    const float* W1 = (const float*)d_in[3];
    const float* b1 = (const float*)d_in[4];
    const float* W2 = (const float*)d_in[5];
    const float* b2 = (const float*)d_in[6];
    const float* W3 = (const float*)d_in[7];
    const float* b3 = (const float*)d_in[8];
    const float* fc1_w = (const float*)d_in[9];
    const float* fc1_b = (const float*)d_in[10];
    const float* fc2_w = (const float*)d_in[11];
    const float* fc2_b = (const float*)d_in[12];
    float* out = (float*)d_out;

    const int DIM = 512, N1 = 256, N2 = 192, N3 = 128, NC = 1000;
    const int n  = in_sizes[0] / DIM;     // 50000
    const int nE = in_sizes[1] / 2;       // 800000
    const int* src = edges;
    const int* dst = edges + nE;

    // workspace layout (bytes)
    char* ws = (char*)d_ws;
    float* bufB    = (float*)(ws);                  // 50000*256*4 = 51,200,000
    int*   deg_i   = (int*)(ws + 51200000);         // 200,000
    float* dinv    = (float*)(ws + 51400000);       // 200,000
    int*   rowptr  = (int*)(ws + 51600000);         // 200,064 (n+1 ints)
    int*   fill    = (int*)(ws + 51800064);         // 200,000
    int*   scanned = (int*)(ws + 52000064);         // 200,704
    int*   bsums   = (int*)(ws + 52200768);         // 256
    int*   eidx    = (int*)(ws + 52201024);         // 3,200,000
    float* ecoef   = (float*)(ws + 55401024);       // 3,200,000
    float* bufA    = out;                           // d_out as 51.2MB scratch (200MB avail)

    hipMemsetAsync(deg_i, 0, (size_t)n * 4, stream);
    hipMemsetAsync(fill, 0, (size_t)n * 4, stream);

    hist_k<<<(nE + 255) / 256, 256, 0, stream>>>(dst, deg_i, nE);
    dinv_k<<<(n + 255) / 256, 256, 0, stream>>>(deg_i, dinv, n);
    int nb = (n + 1023) / 1024;
    scan_block_k<<<nb, 1024, 0, stream>>>(deg_i, scanned, bsums, n);
    scan_sums_k<<<1, 64, 0, stream>>>(bsums, nb);
    scan_final_k<<<(n + 255) / 256, 256, 0, stream>>>(scanned, deg_i, bsums, rowptr, n, nE);
    csr_fill_k<<<(nE + 255) / 256, 256, 0, stream>>>(src, dst, rowptr, fill, dinv, eidx, ecoef, nE);

    int gx = (n + 63) / 64;
    dim3 blk(256);

    // layer 1: xw1 = nodes @ W1 ; x1 = agg(xw1) + b1
    gemm_f32<false, false, false><<<dim3(gx, (N1 + 63) / 64), blk, 0, stream>>>(nodes, W1, nullptr, bufA, n, N1, DIM);
    agg_k<<<(n + 3) / 4, blk, 0, stream>>>(bufA, rowptr, eidx, ecoef, dinv, b1, bufB, n, N1);
    // layer 2
    gemm_f32<false, false, false><<<dim3(gx, (N2 + 63) / 64), blk, 0, stream>>>(bufB, W2, nullptr, bufA, n, N2, N1);
    agg_k<<<(n + 3) / 4, blk, 0, stream>>>(bufA, rowptr, eidx, ecoef, dinv, b2, bufB, n, N2);
    // layer 3
    gemm_f32<false, false, false><<<dim3(gx, (N3 + 63) / 64), blk, 0, stream>>>(bufB, W3, nullptr, bufA, n, N3, N2);
    agg_k<<<(n + 3) / 4, blk, 0, stream>>>(bufA, rowptr, eidx, ecoef, dinv, b3, bufB, n, N3);
    // fc1 (+relu), fc2
    gemm_f32<false, true, true><<<dim3(gx, (N3 + 63) / 64), blk, 0, stream>>>(bufB, fc1_w, fc1_b, bufA, n, N3, N3);
    gemm_f32<false, true, false><<<dim3(gx, (N3 + 63) / 64), blk, 0, stream>>>(bufA, fc2_w, fc2_b, bufB, n, N3, N3);
    // preds = h2 @ labelmatrix^T  (B is [NC][128] row-major -> TRANSB)
    gemm_f32<true, false, false><<<dim3(gx, (NC + 63) / 64), blk, 0, stream>>>(bufB, labelm, nullptr, out, n, NC, N3);
}

// Round 2
// 572.355 us; speedup vs baseline: 1.7245x; 1.7245x over previous
//
#include <hip/hip_runtime.h>

typedef unsigned short u16;
typedef __bf16 bf16x8 __attribute__((ext_vector_type(8)));
typedef float f32x4 __attribute__((ext_vector_type(4)));

__device__ __forceinline__ u16 f2bf(float f) {
    unsigned int u = __float_as_uint(f);
    unsigned int r = (u + 0x7FFFu + ((u >> 16) & 1u)) >> 16;
    return (u16)r;
}
__device__ __forceinline__ float bf2f(u16 h) {
    return __uint_as_float(((unsigned int)h) << 16);
}

// ---------------- graph preprocessing ----------------

__global__ void hist_k(const int* __restrict__ dst, int* __restrict__ deg, int nE) {
    int e = blockIdx.x * 256 + threadIdx.x;
    if (e < nE) atomicAdd(&deg[dst[e]], 1);
}

__global__ void dinv_k(const int* __restrict__ deg, float* __restrict__ dinv, int n) {
    int i = blockIdx.x * 256 + threadIdx.x;
    if (i < n) dinv[i] = rsqrtf((float)deg[i] + 1.0f);
}

__global__ void scan_block_k(const int* __restrict__ deg, int* __restrict__ scanned,
                             int* __restrict__ bsums, int n) {
    __shared__ int s[1024];
    int i = blockIdx.x * 1024 + threadIdx.x;
    int v = (i < n) ? deg[i] : 0;
    s[threadIdx.x] = v;
    __syncthreads();
    for (int off = 1; off < 1024; off <<= 1) {
        int t = (threadIdx.x >= off) ? s[threadIdx.x - off] : 0;
        __syncthreads();
        s[threadIdx.x] += t;
        __syncthreads();
    }
    if (i < n) scanned[i] = s[threadIdx.x];
    if (threadIdx.x == 1023) bsums[blockIdx.x] = s[1023];
}

__global__ void scan_sums_k(int* __restrict__ bsums, int nb) {
    if (threadIdx.x == 0 && blockIdx.x == 0) {
        int acc = 0;
        for (int i = 0; i < nb; ++i) { int v = bsums[i]; bsums[i] = acc; acc += v; }
    }
}

__global__ void scan_final_k(const int* __restrict__ scanned, const int* __restrict__ deg,
                             const int* __restrict__ bsums, int* __restrict__ rowptr,
                             int n, int nE) {
    int i = blockIdx.x * 256 + threadIdx.x;
    if (i < n) rowptr[i] = scanned[i] - deg[i] + bsums[i >> 10];
    if (i == 0) rowptr[n] = nE;
}

__global__ void csr_fill_k(const int* __restrict__ src, const int* __restrict__ dst,
                           const int* __restrict__ rowptr, int* __restrict__ fill,
                           const float* __restrict__ dinv, int* __restrict__ eidx,
                           float* __restrict__ ecoef, int nE) {
    int e = blockIdx.x * 256 + threadIdx.x;
    if (e >= nE) return;
    int d = dst[e], s = src[e];
    int p = rowptr[d] + atomicAdd(&fill[d], 1);
    eidx[p] = s;
    ecoef[p] = dinv[s] * dinv[d];
}

// ---------------- casts / weight prep ----------------

// nodes f32 [n][512] -> bf16 [Mpad][512], pad rows zero
__global__ void cast_nodes_k(const float* __restrict__ src, u16* __restrict__ dst, int n, int total8) {
    int i = blockIdx.x * 256 + threadIdx.x;   // index of 8-element group
    if (i >= total8) return;
    int row = i >> 6;                          // 64 groups of 8 per 512-row
    ushort4 o0, o1;
    if (row < n) {
        const float4* s4 = (const float4*)(src + ((size_t)i << 3));
        float4 a = s4[0], b = s4[1];
        o0.x = f2bf(a.x); o0.y = f2bf(a.y); o0.z = f2bf(a.z); o0.w = f2bf(a.w);
        o1.x = f2bf(b.x); o1.y = f2bf(b.y); o1.z = f2bf(b.z); o1.w = f2bf(b.w);
    } else {
        o0.x = o0.y = o0.z = o0.w = 0;
        o1 = o0;
    }
    ushort4* d4 = (ushort4*)(dst + ((size_t)i << 3));
    d4[0] = o0; d4[1] = o1;
}

// W [K][N] (or already [N][K] if srcNmajor) -> Bt bf16 [Npad][K], pad rows zero
__global__ void prepw_k(const float* __restrict__ src, u16* __restrict__ dst,
                        int K, int N, int Npad, int srcNmajor) {
    int idx = blockIdx.x * 256 + threadIdx.x;
    if (idx >= Npad * K) return;
    int nn = idx / K, k = idx - nn * K;
    float v = 0.f;
    if (nn < N) v = srcNmajor ? src[(size_t)nn * K + k] : src[(size_t)k * N + nn];
    dst[idx] = f2bf(v);
}

// ---------------- bf16 MFMA GEMM ----------------
// C[M,N] = A[Mpad,K](bf16) @ Bt[Npad,K](bf16)^T ; BM=BN=128, BK=64, 4 waves.
// LDS chunk swizzle: chunk' = chunk ^ (row&7)  (chunk = 16B / 8 bf16)

template <bool OUTF32, bool BIAS, bool RELU>
__global__ __launch_bounds__(256) void gemm_mfma(
    const u16* __restrict__ A, const u16* __restrict__ Bt,
    const float* __restrict__ bias, void* __restrict__ Cout,
    int K, int Nout, int ldc, int Mout) {
    __shared__ __align__(16) u16 As[128 * 64];
    __shared__ __align__(16) u16 Bs[128 * 64];
    const int tid  = threadIdx.x;
    const int lane = tid & 63;
    const int w    = tid >> 6;
    const int wm   = w >> 1, wn = w & 1;
    const size_t bm = (size_t)blockIdx.x * 128;
    const size_t bn = (size_t)blockIdx.y * 128;

    const int l7 = lane & 7;
    const int l3 = lane >> 3;
    const int kcs = l7 ^ l3;   // inverse-swizzled source chunk for staging

    f32x4 acc[4][4] = {};

    for (int k0 = 0; k0 < K; k0 += 64) {
#pragma unroll
        for (int it = 0; it < 4; ++it) {
            const int r0 = w * 32 + it * 8;
            const u16* gA = A + ((size_t)(bm + r0 + l3) * K + k0) + kcs * 8;
            __builtin_amdgcn_global_load_lds(
                (const __attribute__((address_space(1))) unsigned int*)gA,
                (__attribute__((address_space(3))) unsigned int*)(As + r0 * 64), 16, 0, 0);
            const u16* gB = Bt + ((size_t)(bn + r0 + l3) * K + k0) + kcs * 8;
            __builtin_amdgcn_global_load_lds(
                (const __attribute__((address_space(1))) unsigned int*)gB,
                (__attribute__((address_space(3))) unsigned int*)(Bs + r0 * 64), 16, 0, 0);
        }
        __syncthreads();

#pragma unroll
        for (int ks = 0; ks < 2; ++ks) {
            bf16x8 av[4], bv[4];
#pragma unroll
            for (int i = 0; i < 4; ++i) {
                int row = wm * 64 + i * 16 + (lane & 15);
                int kc = (ks * 4 + (lane >> 4)) ^ (lane & 7);
                av[i] = *(const bf16x8*)((const char*)As + row * 128 + kc * 16);
            }
#pragma unroll
            for (int j = 0; j < 4; ++j) {
                int nn = wn * 64 + j * 16 + (lane & 15);
                int kc = (ks * 4 + (lane >> 4)) ^ (lane & 7);
                bv[j] = *(const bf16x8*)((const char*)Bs + nn * 128 + kc * 16);
            }
#pragma unroll
            for (int i = 0; i < 4; ++i)
#pragma unroll
                for (int j = 0; j < 4; ++j)
                    acc[i][j] = __builtin_amdgcn_mfma_f32_16x16x32_bf16(av[i], bv[j], acc[i][j], 0, 0, 0);
        }
        __syncthreads();
    }

    const int ccol  = lane & 15;
    const int crow4 = (lane >> 4) * 4;
#pragma unroll
    for (int i = 0; i < 4; ++i) {
#pragma unroll
        for (int j = 0; j < 4; ++j) {
#pragma unroll
            for (int r = 0; r < 4; ++r) {
                size_t gr = bm + wm * 64 + i * 16 + crow4 + r;
                size_t gc = bn + wn * 64 + j * 16 + ccol;
                if (gr < (size_t)Mout && gc < (size_t)Nout) {
                    float v = acc[i][j][r];
                    if constexpr (BIAS) v += bias[gc];
                    if constexpr (RELU) v = fmaxf(v, 0.f);
                    if constexpr (OUTF32) ((float*)Cout)[gr * ldc + gc] = v;
                    else                  ((u16*)Cout)[gr * ldc + gc] = f2bf(v);
                }
            }
        }
    }
}

// ---------------- GCN aggregation (bf16 in/out, f32 accum) ----------------

__global__ __launch_bounds__(256) void agg_bf16(
    const u16* __restrict__ xw, const int* __restrict__ rowptr,
    const int* __restrict__ eidx, const float* __restrict__ ecoef,
    const float* __restrict__ dinv, const float* __restrict__ bias,
    u16* __restrict__ out, int n, int N) {
    int wave = threadIdx.x >> 6, lane = threadIdx.x & 63;
    int node = blockIdx.x * 4 + wave;
    if (node >= n) return;
    int nv = N >> 2;
    if (lane >= nv) return;
    const ushort4* xv = (const ushort4*)xw;
    float di = dinv[node];
    float s = di * di;
    float4 b4 = ((const float4*)bias)[lane];
    ushort4 a = xv[(size_t)node * nv + lane];
    float4 acc;
    acc.x = b4.x + s * bf2f(a.x);
    acc.y = b4.y + s * bf2f(a.y);
    acc.z = b4.z + s * bf2f(a.z);
    acc.w = b4.w + s * bf2f(a.w);
    int beg = rowptr[node], end = rowptr[node + 1];
    for (int e = beg; e < end; ++e) {
        int sn = eidx[e];
        float c = ecoef[e];
        ushort4 v = xv[(size_t)sn * nv + lane];
        acc.x = fmaf(c, bf2f(v.x), acc.x);
        acc.y = fmaf(c, bf2f(v.y), acc.y);
        acc.z = fmaf(c, bf2f(v.z), acc.z);
        acc.w = fmaf(c, bf2f(v.w), acc.w);
    }
    ushort4 o;
    o.x = f2bf(acc.x); o.y = f2bf(acc.y); o.z = f2bf(acc.z); o.w = f2bf(acc.w);
    ((ushort4*)out)[(size_t)node * nv + lane] = o;
}

// ---------------- launcher ----------------

extern "C" void kernel_launch(void* const* d_in, const int* in_sizes, int n_in,
                              void* d_out, int out_size, void* d_ws, size_t ws_size,
                              hipStream_t stream) {
    const float* nodes  = (const float*)d_in[0];
    const int*   edges  = (const int*)d_in[1];
    const float* labelm = (const float*)d_in[2];
    const float* W1 = (const float*)d_in[3];
    const float* b1 = (const float*)d_in[4];
    const float* W2 = (const float*)d_in[5];
    const float* b2 = (const float*)d_in[6];
    const float* W3 = (const float*)d_in[7];
    const float* b3 = (const float*)d_in[8];
    const float* fc1_w = (const float*)d_in[9];
    const float* fc1_b = (const float*)d_in[10];
    const float* fc2_w = (const float*)d_in[11];
    const float* fc2_b = (const float*)d_in[12];
    float* out = (float*)d_out;

    const int DIM = 512, N1 = 256, N2 = 192, N3 = 128, NC = 1000;
    const int n  = in_sizes[0] / DIM;   // 50000
    const int nE = in_sizes[1] / 2;     // 800000
    const int Mpad = 50048;             // 391 * 128
    const int* src = edges;
    const int* dst = edges + nE;

    // d_out scratch: nodes_bf [0, 51.25MB), P at 64MB (25.6MB). Both dead before preds write.
    u16* nodes_bf = (u16*)d_out;
    u16* P        = (u16*)((char*)d_out + 67108864);

    // ws layout
    char* ws = (char*)d_ws;
    u16*   Q      = (u16*)(ws);                      // 50048*256*2 = 25,624,576
    u16*   Bt1    = (u16*)(ws + 25624576);           // 256*512*2  =    262,144
    u16*   Bt2    = (u16*)(ws + 25886720);           // 256*256*2  =    131,072
    u16*   Bt3    = (u16*)(ws + 26017792);           // 128*192*2  =     49,152
    u16*   Bfc1   = (u16*)(ws + 26066944);           // 128*128*2  =     32,768
    u16*   Bfc2   = (u16*)(ws + 26099712);           // 128*128*2  =     32,768
    u16*   Blab   = (u16*)(ws + 26132480);           // 1024*128*2 =    262,144
    int*   deg_i  = (int*)(ws + 26394624);           // 200,000
    float* dinv   = (float*)(ws + 26594624);         // 200,000
    int*   rowptr = (int*)(ws + 26794624);           // 200,064
    int*   fill   = (int*)(ws + 26994688);           // 200,000
    int*   scanned= (int*)(ws + 27194688);           // 200,000
    int*   bsums  = (int*)(ws + 27394688);           // 256
    int*   eidx   = (int*)(ws + 27394944);           // 3,200,000
    float* ecoef  = (float*)(ws + 30594944);         // 3,200,000  (end ~33.8MB)

    hipMemsetAsync(deg_i, 0, (size_t)n * 4, stream);
    hipMemsetAsync(fill, 0, (size_t)n * 4, stream);

    hist_k<<<(nE + 255) / 256, 256, 0, stream>>>(dst, deg_i, nE);
    dinv_k<<<(n + 255) / 256, 256, 0, stream>>>(deg_i, dinv, n);
    int nb = (n + 1023) / 1024;
    scan_block_k<<<nb, 1024, 0, stream>>>(deg_i, scanned, bsums, n);
    scan_sums_k<<<1, 64, 0, stream>>>(bsums, nb);
    scan_final_k<<<(n + 255) / 256, 256, 0, stream>>>(scanned, deg_i, bsums, rowptr, n, nE);
    csr_fill_k<<<(nE + 255) / 256, 256, 0, stream>>>(src, dst, rowptr, fill, dinv, eidx, ecoef, nE);

    // casts
    int total8 = Mpad * (DIM / 8);
    cast_nodes_k<<<(total8 + 255) / 256, 256, 0, stream>>>(nodes, nodes_bf, n, total8);
    prepw_k<<<(256 * 512 + 255) / 256, 256, 0, stream>>>(W1, Bt1, 512, 256, 256, 0);
    prepw_k<<<(256 * 256 + 255) / 256, 256, 0, stream>>>(W2, Bt2, 256, 192, 256, 0);
    prepw_k<<<(128 * 192 + 255) / 256, 256, 0, stream>>>(W3, Bt3, 192, 128, 128, 0);
    prepw_k<<<(128 * 128 + 255) / 256, 256, 0, stream>>>(fc1_w, Bfc1, 128, 128, 128, 0);
    prepw_k<<<(128 * 128 + 255) / 256, 256, 0, stream>>>(fc2_w, Bfc2, 128, 128, 128, 0);
    prepw_k<<<(1024 * 128 + 255) / 256, 256, 0, stream>>>(labelm, Blab, 128, 1000, 1024, 1);

    const int gx = Mpad / 128;  // 391
    dim3 blk(256);

    // layer 1
    gemm_mfma<false, false, false><<<dim3(gx, 2), blk, 0, stream>>>(nodes_bf, Bt1, nullptr, P, 512, N1, N1, Mpad);
    agg_bf16<<<(n + 3) / 4, blk, 0, stream>>>(P, rowptr, eidx, ecoef, dinv, b1, Q, n, N1);
    // layer 2
    gemm_mfma<false, false, false><<<dim3(gx, 2), blk, 0, stream>>>(Q, Bt2, nullptr, P, 256, N2, N2, Mpad);
    agg_bf16<<<(n + 3) / 4, blk, 0, stream>>>(P, rowptr, eidx, ecoef, dinv, b2, Q, n, N2);
    // layer 3
    gemm_mfma<false, false, false><<<dim3(gx, 1), blk, 0, stream>>>(Q, Bt3, nullptr, P, 192, N3, N3, Mpad);
    agg_bf16<<<(n + 3) / 4, blk, 0, stream>>>(P, rowptr, eidx, ecoef, dinv, b3, Q, n, N3);
    // fc1 (+relu) -> P, fc2 -> Q
    gemm_mfma<false, true, true ><<<dim3(gx, 1), blk, 0, stream>>>(Q, Bfc1, fc1_b, P, 128, N3, N3, Mpad);
    gemm_mfma<false, true, false><<<dim3(gx, 1), blk, 0, stream>>>(P, Bfc2, fc2_b, Q, 128, N3, N3, Mpad);
    // preds: A=Q (ws), write f32 d_out [50000 x 1000]
    gemm_mfma<true, false, false><<<dim3(gx, 8), blk, 0, stream>>>(Q, Blab, nullptr, out, 128, NC, NC, n);
}

// Round 3
// 472.775 us; speedup vs baseline: 2.0877x; 1.2106x over previous
//
#include <hip/hip_runtime.h>

typedef unsigned short u16;
typedef __bf16 bf16x8 __attribute__((ext_vector_type(8)));
typedef float f32x4 __attribute__((ext_vector_type(4)));

__device__ __forceinline__ u16 f2bf(float f) {
    unsigned int u = __float_as_uint(f);
    unsigned int r = (u + 0x7FFFu + ((u >> 16) & 1u)) >> 16;
    return (u16)r;
}
__device__ __forceinline__ float bf_lo(unsigned int u) { return __uint_as_float(u << 16); }
__device__ __forceinline__ float bf_hi(unsigned int u) { return __uint_as_float(u & 0xFFFF0000u); }

// ---------------- graph preprocessing ----------------

__global__ void zero2_k(int* __restrict__ a, int* __restrict__ b, int n) {
    int i = blockIdx.x * 256 + threadIdx.x;
    if (i < n) { a[i] = 0; b[i] = 0; }
}

__global__ void hist_k(const int* __restrict__ dst, int* __restrict__ deg, int nE) {
    int e = blockIdx.x * 256 + threadIdx.x;
    if (e < nE) atomicAdd(&deg[dst[e]], 1);
}

__global__ void scan_block_k(const int* __restrict__ deg, int* __restrict__ scanned,
                             int* __restrict__ bsums, int n) {
    __shared__ int s[1024];
    int i = blockIdx.x * 1024 + threadIdx.x;
    int v = (i < n) ? deg[i] : 0;
    s[threadIdx.x] = v;
    __syncthreads();
    for (int off = 1; off < 1024; off <<= 1) {
        int t = (threadIdx.x >= off) ? s[threadIdx.x - off] : 0;
        __syncthreads();
        s[threadIdx.x] += t;
        __syncthreads();
    }
    if (i < n) scanned[i] = s[threadIdx.x];
    if (threadIdx.x == 1023) bsums[blockIdx.x] = s[1023];
}

// nb <= 64: one-wave exclusive scan
__global__ void scan_sums_k(int* __restrict__ bsums, int nb) {
    int l = threadIdx.x & 63;
    int v = (l < nb) ? bsums[l] : 0;
    int orig = v;
    for (int off = 1; off < 64; off <<= 1) {
        int t = __shfl_up(v, off);
        if (l >= off) v += t;
    }
    if (l < nb) bsums[l] = v - orig;
}

__global__ void scan_final_dinv_k(const int* __restrict__ scanned, const int* __restrict__ deg,
                                  const int* __restrict__ bsums, int* __restrict__ rowptr,
                                  float* __restrict__ dinv, int n, int nE) {
    int i = blockIdx.x * 256 + threadIdx.x;
    if (i < n) {
        rowptr[i] = scanned[i] - deg[i] + bsums[i >> 10];
        dinv[i] = rsqrtf((float)deg[i] + 1.0f);
    }
    if (i == 0) rowptr[n] = nE;
}

__global__ void csr_fill_k(const int* __restrict__ src, const int* __restrict__ dst,
                           const int* __restrict__ rowptr, int* __restrict__ fill,
                           const float* __restrict__ dinv, int* __restrict__ eidx,
                           float* __restrict__ ecoef, int nE) {
    int e = blockIdx.x * 256 + threadIdx.x;
    if (e >= nE) return;
    int d = dst[e], s = src[e];
    int p = rowptr[d] + atomicAdd(&fill[d], 1);
    eidx[p] = s;
    ecoef[p] = dinv[s] * dinv[d];
}

// ---------------- casts / weight prep ----------------

__global__ void cast_nodes_k(const float* __restrict__ src, u16* __restrict__ dst, int n, int total8) {
    int i = blockIdx.x * 256 + threadIdx.x;
    if (i >= total8) return;
    int row = i >> 6;
    ushort4 o0, o1;
    if (row < n) {
        const float4* s4 = (const float4*)(src + ((size_t)i << 3));
        float4 a = s4[0], b = s4[1];
        o0.x = f2bf(a.x); o0.y = f2bf(a.y); o0.z = f2bf(a.z); o0.w = f2bf(a.w);
        o1.x = f2bf(b.x); o1.y = f2bf(b.y); o1.z = f2bf(b.z); o1.w = f2bf(b.w);
    } else {
        o0.x = o0.y = o0.z = o0.w = 0;
        o1 = o0;
    }
    ushort4* d4 = (ushort4*)(dst + ((size_t)i << 3));
    d4[0] = o0; d4[1] = o1;
}

// all 4 weight transposes in one launch. src [K][N] -> dst [Npad][K] bf16
__global__ void prepw_all_k(const float* __restrict__ W1, u16* __restrict__ Bt1,
                            const float* __restrict__ W2, u16* __restrict__ Bt2,
                            const float* __restrict__ W3, u16* __restrict__ Bt3,
                            const float* __restrict__ Wf1, u16* __restrict__ Bf1) {
    int b = blockIdx.x;
    const float* src; u16* dst; int K, N, Npad, base;
    if (b < 512)      { src = W1;  dst = Bt1; K = 512; N = 256; Npad = 256; base = 0; }
    else if (b < 768) { src = W2;  dst = Bt2; K = 256; N = 192; Npad = 256; base = 512; }
    else if (b < 864) { src = W3;  dst = Bt3; K = 192; N = 128; Npad = 128; base = 768; }
    else              { src = Wf1; dst = Bf1; K = 128; N = 128; Npad = 128; base = 864; }
    int idx = (b - base) * 256 + threadIdx.x;
    if (idx >= Npad * K) return;
    int nn = idx / K, k = idx - nn * K;
    float v = (nn < N) ? src[(size_t)k * N + nn] : 0.f;
    dst[idx] = f2bf(v);
}

// Wc[c][k] = sum_j fc2_w[k][j]*labelm[c][j]  (bf16, [1024][128]); bc[c] = dot(fc2_b, labelm[c])
__global__ __launch_bounds__(128) void fuse_fc2_k(
    const float* __restrict__ fc2_w, const float* __restrict__ fc2_b,
    const float* __restrict__ labelm, u16* __restrict__ Wc, float* __restrict__ bc) {
    __shared__ float w[128 * 129];
    __shared__ float lm[128];
    __shared__ float red[2];
    const int tid = threadIdx.x;
    for (int t = tid; t < 128 * 128; t += 128)
        w[(t >> 7) * 129 + (t & 127)] = fc2_w[t];
    __syncthreads();
    for (int cc = 0; cc < 8; ++cc) {
        int c = blockIdx.x * 8 + cc;
        lm[tid] = (c < 1000) ? labelm[(size_t)c * 128 + tid] : 0.f;
        __syncthreads();
        float sum = 0.f;
        const float* wr = &w[tid * 129];
        for (int j = 0; j < 128; ++j) sum = fmaf(wr[j], lm[j], sum);
        Wc[(size_t)c * 128 + tid] = f2bf(sum);
        // bias reduce
        float p = fc2_b[tid] * lm[tid];
        for (int off = 32; off > 0; off >>= 1) p += __shfl_down(p, off);
        if ((tid & 63) == 0) red[tid >> 6] = p;
        __syncthreads();
        if (tid == 0) bc[c] = red[0] + red[1];
        __syncthreads();
    }
}

// ---------------- bf16 MFMA GEMM ----------------
// C[M,N] = A[Mpad,K](bf16) @ Bt[Npad,K](bf16)^T ; BM=BN=128, BK=64, 4 waves.

template <bool OUTF32, bool BIAS, bool RELU>
__global__ __launch_bounds__(256) void gemm_mfma(
    const u16* __restrict__ A, const u16* __restrict__ Bt,
    const float* __restrict__ bias, void* __restrict__ Cout,
    int K, int Nout, int ldc, int Mout) {
    __shared__ __align__(16) u16 As[128 * 64];
    __shared__ __align__(16) u16 Bs[128 * 64];
    const int tid  = threadIdx.x;
    const int lane = tid & 63;
    const int w    = tid >> 6;
    const int wm   = w >> 1, wn = w & 1;
    const size_t bm = (size_t)blockIdx.x * 128;
    const size_t bn = (size_t)blockIdx.y * 128;

    const int l7 = lane & 7;
    const int l3 = lane >> 3;
    const int kcs = l7 ^ l3;

    f32x4 acc[4][4] = {};

    for (int k0 = 0; k0 < K; k0 += 64) {
#pragma unroll
        for (int it = 0; it < 4; ++it) {
            const int r0 = w * 32 + it * 8;
            const u16* gA = A + ((size_t)(bm + r0 + l3) * K + k0) + kcs * 8;
            __builtin_amdgcn_global_load_lds(
                (const __attribute__((address_space(1))) unsigned int*)gA,
                (__attribute__((address_space(3))) unsigned int*)(As + r0 * 64), 16, 0, 0);
            const u16* gB = Bt + ((size_t)(bn + r0 + l3) * K + k0) + kcs * 8;
            __builtin_amdgcn_global_load_lds(
                (const __attribute__((address_space(1))) unsigned int*)gB,
                (__attribute__((address_space(3))) unsigned int*)(Bs + r0 * 64), 16, 0, 0);
        }
        __syncthreads();

#pragma unroll
        for (int ks = 0; ks < 2; ++ks) {
            bf16x8 av[4], bv[4];
#pragma unroll
            for (int i = 0; i < 4; ++i) {
                int row = wm * 64 + i * 16 + (lane & 15);
                int kc = (ks * 4 + (lane >> 4)) ^ (lane & 7);
                av[i] = *(const bf16x8*)((const char*)As + row * 128 + kc * 16);
            }
#pragma unroll
            for (int j = 0; j < 4; ++j) {
                int nn = wn * 64 + j * 16 + (lane & 15);
                int kc = (ks * 4 + (lane >> 4)) ^ (lane & 7);
                bv[j] = *(const bf16x8*)((const char*)Bs + nn * 128 + kc * 16);
            }
#pragma unroll
            for (int i = 0; i < 4; ++i)
#pragma unroll
                for (int j = 0; j < 4; ++j)
                    acc[i][j] = __builtin_amdgcn_mfma_f32_16x16x32_bf16(av[i], bv[j], acc[i][j], 0, 0, 0);
        }
        __syncthreads();
    }

    const int ccol  = lane & 15;
    const int crow4 = (lane >> 4) * 4;
#pragma unroll
    for (int i = 0; i < 4; ++i) {
#pragma unroll
        for (int j = 0; j < 4; ++j) {
#pragma unroll
            for (int r = 0; r < 4; ++r) {
                size_t gr = bm + wm * 64 + i * 16 + crow4 + r;
                size_t gc = bn + wn * 64 + j * 16 + ccol;
                if (gr < (size_t)Mout && gc < (size_t)Nout) {
                    float v = acc[i][j][r];
                    if constexpr (BIAS) v += bias[gc];
                    if constexpr (RELU) v = fmaxf(v, 0.f);
                    if constexpr (OUTF32) ((float*)Cout)[gr * ldc + gc] = v;
                    else                  ((u16*)Cout)[gr * ldc + gc] = f2bf(v);
                }
            }
        }
    }
}

// ---------------- GCN aggregation: multi-node/wave, 16B loads ----------------

template <int NFEAT>
__global__ __launch_bounds__(256) void agg2_k(
    const u16* __restrict__ xw, const int* __restrict__ rowptr,
    const int* __restrict__ eidx, const float* __restrict__ ecoef,
    const float* __restrict__ dinv, const float* __restrict__ bias,
    u16* __restrict__ out, int n) {
    constexpr int LPN = NFEAT / 8;   // lanes per node (32/24/16)
    constexpr int NPW = 64 / LPN;    // nodes per wave (2/2/4)
    const int wave = threadIdx.x >> 6, lane = threadIdx.x & 63;
    const int sub = lane / LPN;
    const int fl  = lane - sub * LPN;
    if (sub >= NPW) return;
    int node = (blockIdx.x * 4 + wave) * NPW + sub;
    if (node >= n) return;

    const uint4* xv = (const uint4*)xw;   // 8 bf16 per uint4
    float di = dinv[node];
    float s = di * di;
    float4 b0 = ((const float4*)bias)[fl * 2];
    float4 b1 = ((const float4*)bias)[fl * 2 + 1];
    uint4 a = xv[(size_t)node * LPN + fl];
    float acc[8];
    acc[0] = b0.x + s * bf_lo(a.x); acc[1] = b0.y + s * bf_hi(a.x);
    acc[2] = b0.z + s * bf_lo(a.y); acc[3] = b0.w + s * bf_hi(a.y);
    acc[4] = b1.x + s * bf_lo(a.z); acc[5] = b1.y + s * bf_hi(a.z);
    acc[6] = b1.z + s * bf_lo(a.w); acc[7] = b1.w + s * bf_hi(a.w);

    int beg = rowptr[node], end = rowptr[node + 1];
    for (int e = beg; e < end; ++e) {
        int sn = eidx[e];
        float c = ecoef[e];
        uint4 v = xv[(size_t)sn * LPN + fl];
        acc[0] = fmaf(c, bf_lo(v.x), acc[0]); acc[1] = fmaf(c, bf_hi(v.x), acc[1]);
        acc[2] = fmaf(c, bf_lo(v.y), acc[2]); acc[3] = fmaf(c, bf_hi(v.y), acc[3]);
        acc[4] = fmaf(c, bf_lo(v.z), acc[4]); acc[5] = fmaf(c, bf_hi(v.z), acc[5]);
        acc[6] = fmaf(c, bf_lo(v.w), acc[6]); acc[7] = fmaf(c, bf_hi(v.w), acc[7]);
    }
    uint4 o;
    o.x = (unsigned)f2bf(acc[0]) | ((unsigned)f2bf(acc[1]) << 16);
    o.y = (unsigned)f2bf(acc[2]) | ((unsigned)f2bf(acc[3]) << 16);
    o.z = (unsigned)f2bf(acc[4]) | ((unsigned)f2bf(acc[5]) << 16);
    o.w = (unsigned)f2bf(acc[6]) | ((unsigned)f2bf(acc[7]) << 16);
    ((uint4*)out)[(size_t)node * LPN + fl] = o;
}

// ---------------- launcher ----------------

extern "C" void kernel_launch(void* const* d_in, const int* in_sizes, int n_in,
                              void* d_out, int out_size, void* d_ws, size_t ws_size,
                              hipStream_t stream) {
    const float* nodes  = (const float*)d_in[0];
    const int*   edges  = (const int*)d_in[1];
    const float* labelm = (const float*)d_in[2];
    const float* W1 = (const float*)d_in[3];
    const float* b1 = (const float*)d_in[4];
    const float* W2 = (const float*)d_in[5];
    const float* b2 = (const float*)d_in[6];
    const float* W3 = (const float*)d_in[7];
    const float* b3 = (const float*)d_in[8];
    const float* fc1_w = (const float*)d_in[9];
    const float* fc1_b = (const float*)d_in[10];
    const float* fc2_w = (const float*)d_in[11];
    const float* fc2_b = (const float*)d_in[12];
    float* out = (float*)d_out;

    const int DIM = 512, N1 = 256, N2 = 192, N3 = 128, NC = 1000;
    const int n  = in_sizes[0] / DIM;   // 50000
    const int nE = in_sizes[1] / 2;     // 800000
    const int Mpad = 50048;             // 391 * 128
    const int* src = edges;
    const int* dst = edges + nE;

    // d_out scratch (200MB total): all dead before preds writes
    u16* nodes_bf = (u16*)d_out;                          // 51.25MB
    u16* P        = (u16*)((char*)d_out + 67108864);      // 25.6MB
    u16* R        = (u16*)((char*)d_out + 100000000);     // 12.8MB

    // ws layout
    char* ws = (char*)d_ws;
    u16*   Q      = (u16*)(ws);                  // 25,624,576
    u16*   Bt1    = (u16*)(ws + 25624576);       // 262,144
    u16*   Bt2    = (u16*)(ws + 25886720);       // 131,072
    u16*   Bt3    = (u16*)(ws + 26017792);       // 49,152
    u16*   Bfc1   = (u16*)(ws + 26066944);       // 32,768
    u16*   Wc     = (u16*)(ws + 26099712);       // 1024*128*2 = 262,144
    float* bc     = (float*)(ws + 26361856);     // 4,096
    int*   deg_i  = (int*)(ws + 26365952);       // 200,000
    float* dinv   = (float*)(ws + 26565952);     // 200,000
    int*   rowptr = (int*)(ws + 26765952);       // 200,064
    int*   fill   = (int*)(ws + 26966016);       // 200,000
    int*   scanned= (int*)(ws + 27166016);       // 200,000
    int*   bsums  = (int*)(ws + 27366016);       // 256
    int*   eidx   = (int*)(ws + 27366272);       // 3,200,000
    float* ecoef  = (float*)(ws + 30566272);     // 3,200,000 (end 33.77MB)

    zero2_k<<<(n + 255) / 256, 256, 0, stream>>>(deg_i, fill, n);
    hist_k<<<(nE + 255) / 256, 256, 0, stream>>>(dst, deg_i, nE);
    int nb = (n + 1023) / 1024;
    scan_block_k<<<nb, 1024, 0, stream>>>(deg_i, scanned, bsums, n);
    scan_sums_k<<<1, 64, 0, stream>>>(bsums, nb);
    scan_final_dinv_k<<<(n + 255) / 256, 256, 0, stream>>>(scanned, deg_i, bsums, rowptr, dinv, n, nE);
    csr_fill_k<<<(nE + 255) / 256, 256, 0, stream>>>(src, dst, rowptr, fill, dinv, eidx, ecoef, nE);

    int total8 = Mpad * (DIM / 8);
    cast_nodes_k<<<(total8 + 255) / 256, 256, 0, stream>>>(nodes, nodes_bf, n, total8);
    prepw_all_k<<<928, 256, 0, stream>>>(W1, Bt1, W2, Bt2, W3, Bt3, fc1_w, Bfc1);
    fuse_fc2_k<<<128, 128, 0, stream>>>(fc2_w, fc2_b, labelm, Wc, bc);

    const int gx = Mpad / 128;  // 391
    dim3 blk(256);

    // layer 1: nodes_bf -> P -> Q
    gemm_mfma<false, false, false><<<dim3(gx, 2), blk, 0, stream>>>(nodes_bf, Bt1, nullptr, P, 512, N1, N1, Mpad);
    agg2_k<256><<<(n + 7) / 8, blk, 0, stream>>>(P, rowptr, eidx, ecoef, dinv, b1, Q, n);
    // layer 2: Q -> P -> Q
    gemm_mfma<false, false, false><<<dim3(gx, 2), blk, 0, stream>>>(Q, Bt2, nullptr, P, 256, N2, N2, Mpad);
    agg2_k<192><<<(n + 7) / 8, blk, 0, stream>>>(P, rowptr, eidx, ecoef, dinv, b2, Q, n);
    // layer 3: Q -> P -> R
    gemm_mfma<false, false, false><<<dim3(gx, 1), blk, 0, stream>>>(Q, Bt3, nullptr, P, 192, N3, N3, Mpad);
    agg2_k<128><<<(n + 15) / 16, blk, 0, stream>>>(P, rowptr, eidx, ecoef, dinv, b3, R, n);
    // fc1 (+relu): R -> Q
    gemm_mfma<false, true, true><<<dim3(gx, 1), blk, 0, stream>>>(R, Bfc1, fc1_b, Q, 128, N3, N3, Mpad);
    // preds (fc2 folded into Wc/bc): Q -> out
    gemm_mfma<true, true, false><<<dim3(gx, 8), blk, 0, stream>>>(Q, Wc, bc, out, 128, NC, NC, n);
}

// Round 4
// 441.944 us; speedup vs baseline: 2.2334x; 1.0698x over previous
//
#include <hip/hip_runtime.h>

typedef unsigned short u16;
typedef __bf16 bf16x8 __attribute__((ext_vector_type(8)));
typedef float f32x4 __attribute__((ext_vector_type(4)));

__device__ __forceinline__ u16 f2bf(float f) {
    unsigned int u = __float_as_uint(f);
    unsigned int r = (u + 0x7FFFu + ((u >> 16) & 1u)) >> 16;
    return (u16)r;
}
__device__ __forceinline__ float bf_lo(unsigned int u) { return __uint_as_float(u << 16); }
__device__ __forceinline__ float bf_hi(unsigned int u) { return __uint_as_float(u & 0xFFFF0000u); }

// ---------------- graph preprocessing ----------------

__global__ void zero2_k(int* __restrict__ a, int* __restrict__ b, int n) {
    int i = blockIdx.x * 256 + threadIdx.x;
    if (i < n) { a[i] = 0; b[i] = 0; }
}

__global__ void hist_k(const int* __restrict__ dst, int* __restrict__ deg, int nE) {
    int e = blockIdx.x * 256 + threadIdx.x;
    if (e < nE) atomicAdd(&deg[dst[e]], 1);
}

__global__ void scan_block_k(const int* __restrict__ deg, int* __restrict__ scanned,
                             int* __restrict__ bsums, int n) {
    __shared__ int s[1024];
    int i = blockIdx.x * 1024 + threadIdx.x;
    int v = (i < n) ? deg[i] : 0;
    s[threadIdx.x] = v;
    __syncthreads();
    for (int off = 1; off < 1024; off <<= 1) {
        int t = (threadIdx.x >= off) ? s[threadIdx.x - off] : 0;
        __syncthreads();
        s[threadIdx.x] += t;
        __syncthreads();
    }
    if (i < n) scanned[i] = s[threadIdx.x];
    if (threadIdx.x == 1023) bsums[blockIdx.x] = s[1023];
}

__global__ void scan_sums_k(int* __restrict__ bsums, int nb) {
    int l = threadIdx.x & 63;
    int v = (l < nb) ? bsums[l] : 0;
    int orig = v;
    for (int off = 1; off < 64; off <<= 1) {
        int t = __shfl_up(v, off);
        if (l >= off) v += t;
    }
    if (l < nb) bsums[l] = v - orig;
}

__global__ void scan_final_dinv_k(const int* __restrict__ scanned, const int* __restrict__ deg,
                                  const int* __restrict__ bsums, int* __restrict__ rowptr,
                                  float* __restrict__ dinv, int n, int nE) {
    int i = blockIdx.x * 256 + threadIdx.x;
    if (i < n) {
        rowptr[i] = scanned[i] - deg[i] + bsums[i >> 10];
        dinv[i] = rsqrtf((float)deg[i] + 1.0f);
    }
    if (i == 0) rowptr[n] = nE;
}

__global__ void csr_fill_k(const int* __restrict__ src, const int* __restrict__ dst,
                           const int* __restrict__ rowptr, int* __restrict__ fill,
                           const float* __restrict__ dinv, int* __restrict__ eidx,
                           float* __restrict__ ecoef, int nE) {
    int e = blockIdx.x * 256 + threadIdx.x;
    if (e >= nE) return;
    int d = dst[e], s = src[e];
    int p = rowptr[d] + atomicAdd(&fill[d], 1);
    eidx[p] = s;
    ecoef[p] = dinv[s] * dinv[d];
}

// ---------------- weight prep ----------------

__global__ void prepw_all_k(const float* __restrict__ W1, u16* __restrict__ Bt1,
                            const float* __restrict__ W2, u16* __restrict__ Bt2,
                            const float* __restrict__ W3, u16* __restrict__ Bt3,
                            const float* __restrict__ Wf1, u16* __restrict__ Bf1) {
    int b = blockIdx.x;
    const float* src; u16* dst; int K, N, Npad, base;
    if (b < 512)      { src = W1;  dst = Bt1; K = 512; N = 256; Npad = 256; base = 0; }
    else if (b < 768) { src = W2;  dst = Bt2; K = 256; N = 192; Npad = 256; base = 512; }
    else if (b < 864) { src = W3;  dst = Bt3; K = 192; N = 128; Npad = 128; base = 768; }
    else              { src = Wf1; dst = Bf1; K = 128; N = 128; Npad = 128; base = 864; }
    int idx = (b - base) * 256 + threadIdx.x;
    if (idx >= Npad * K) return;
    int nn = idx / K, k = idx - nn * K;
    float v = (nn < N) ? src[(size_t)k * N + nn] : 0.f;
    dst[idx] = f2bf(v);
}

// Wc[c][k] = sum_j fc2_w[k][j]*labelm[c][j]  (bf16, [1024][128]); bc[c] = dot(fc2_b, labelm[c])
__global__ __launch_bounds__(128) void fuse_fc2_k(
    const float* __restrict__ fc2_w, const float* __restrict__ fc2_b,
    const float* __restrict__ labelm, u16* __restrict__ Wc, float* __restrict__ bc) {
    __shared__ float w[128 * 129];
    __shared__ float lm[128];
    __shared__ float red[2];
    const int tid = threadIdx.x;
    for (int t = tid; t < 128 * 128; t += 128)
        w[(t >> 7) * 129 + (t & 127)] = fc2_w[t];
    __syncthreads();
    for (int cc = 0; cc < 8; ++cc) {
        int c = blockIdx.x * 8 + cc;
        lm[tid] = (c < 1000) ? labelm[(size_t)c * 128 + tid] : 0.f;
        __syncthreads();
        float sum = 0.f;
        const float* wr = &w[tid * 129];
        for (int j = 0; j < 128; ++j) sum = fmaf(wr[j], lm[j], sum);
        Wc[(size_t)c * 128 + tid] = f2bf(sum);
        float p = fc2_b[tid] * lm[tid];
        for (int off = 32; off > 0; off >>= 1) p += __shfl_down(p, off);
        if ((tid & 63) == 0) red[tid >> 6] = p;
        __syncthreads();
        if (tid == 0) bc[c] = red[0] + red[1];
        __syncthreads();
    }
}

// ---------------- bf16 MFMA GEMM ----------------
// C = A @ Bt^T. BM=BN=128, BK=64, 4 waves. 1D grid, XCD-chunked swizzle, N-block inner.
// CASTA: A is f32, cast+swizzle-staged through registers (rows >= Arows -> 0).

template <bool CASTA, bool OUTF32, bool BIAS, bool RELU>
__global__ __launch_bounds__(256) void gemm_mfma(
    const void* __restrict__ Ap, const u16* __restrict__ Bt,
    const float* __restrict__ bias, void* __restrict__ Cout,
    int K, int Nout, int ldc, int Mout, int lgny, int Arows) {
    __shared__ __align__(16) u16 As[128 * 64];
    __shared__ __align__(16) u16 Bs[128 * 64];
    const int tid  = threadIdx.x;
    const int lane = tid & 63;
    const int w    = tid >> 6;
    const int wm   = w >> 1, wn = w & 1;

    // bijective XCD-chunked swizzle (m204): consecutive tiles -> same XCD
    const int nwg = gridDim.x, orig = blockIdx.x;
    const int q = nwg >> 3, r = nwg & 7;
    const int xcd = orig & 7, off = orig >> 3;
    const int tile = (xcd < r ? xcd * (q + 1) : r * (q + 1) + (xcd - r) * q) + off;
    const int ny = 1 << lgny;
    const int tx = tile >> lgny, ty = tile & (ny - 1);
    const size_t bm = (size_t)tx * 128;
    const size_t bn = (size_t)ty * 128;

    const int l7 = lane & 7;
    const int l3 = lane >> 3;
    const int kcs = l7 ^ l3;

    f32x4 acc[4][4] = {};

    for (int k0 = 0; k0 < K; k0 += 64) {
        if constexpr (CASTA) {
            // A: f32 -> bf16, reg-staged, same XOR-chunk layout as load_lds path
            const float* Af = (const float*)Ap;
            const int row = tid >> 1;
            const int half = tid & 1;
            const size_t grow = bm + row;
            const bool valid = grow < (size_t)Arows;
            const float4* g4 = (const float4*)(Af + grow * K + k0 + half * 32);
            float4 f[8];
#pragma unroll
            for (int j = 0; j < 8; ++j)
                f[j] = valid ? g4[j] : make_float4(0.f, 0.f, 0.f, 0.f);
#pragma unroll
            for (int j = 0; j < 4; ++j) {
                int kc = (half * 4 + j) ^ (row & 7);
                uint4 o;
                o.x = (unsigned)f2bf(f[2 * j].x)     | ((unsigned)f2bf(f[2 * j].y) << 16);
                o.y = (unsigned)f2bf(f[2 * j].z)     | ((unsigned)f2bf(f[2 * j].w) << 16);
                o.z = (unsigned)f2bf(f[2 * j + 1].x) | ((unsigned)f2bf(f[2 * j + 1].y) << 16);
                o.w = (unsigned)f2bf(f[2 * j + 1].z) | ((unsigned)f2bf(f[2 * j + 1].w) << 16);
                *(uint4*)((char*)As + row * 128 + kc * 16) = o;
            }
#pragma unroll
            for (int it = 0; it < 4; ++it) {
                const int r0 = w * 32 + it * 8;
                const u16* gB = Bt + ((size_t)(bn + r0 + l3) * K + k0) + kcs * 8;
                __builtin_amdgcn_global_load_lds(
                    (const __attribute__((address_space(1))) unsigned int*)gB,
                    (__attribute__((address_space(3))) unsigned int*)(Bs + r0 * 64), 16, 0, 0);
            }
        } else {
            const u16* A = (const u16*)Ap;
#pragma unroll
            for (int it = 0; it < 4; ++it) {
                const int r0 = w * 32 + it * 8;
                const u16* gA = A + ((size_t)(bm + r0 + l3) * K + k0) + kcs * 8;
                __builtin_amdgcn_global_load_lds(
                    (const __attribute__((address_space(1))) unsigned int*)gA,
                    (__attribute__((address_space(3))) unsigned int*)(As + r0 * 64), 16, 0, 0);
                const u16* gB = Bt + ((size_t)(bn + r0 + l3) * K + k0) + kcs * 8;
                __builtin_amdgcn_global_load_lds(
                    (const __attribute__((address_space(1))) unsigned int*)gB,
                    (__attribute__((address_space(3))) unsigned int*)(Bs + r0 * 64), 16, 0, 0);
            }
        }
        __syncthreads();

#pragma unroll
        for (int ks = 0; ks < 2; ++ks) {
            bf16x8 av[4], bv[4];
#pragma unroll
            for (int i = 0; i < 4; ++i) {
                int row = wm * 64 + i * 16 + (lane & 15);
                int kc = (ks * 4 + (lane >> 4)) ^ (lane & 7);
                av[i] = *(const bf16x8*)((const char*)As + row * 128 + kc * 16);
            }
#pragma unroll
            for (int j = 0; j < 4; ++j) {
                int nn = wn * 64 + j * 16 + (lane & 15);
                int kc = (ks * 4 + (lane >> 4)) ^ (lane & 7);
                bv[j] = *(const bf16x8*)((const char*)Bs + nn * 128 + kc * 16);
            }
#pragma unroll
            for (int i = 0; i < 4; ++i)
#pragma unroll
                for (int j = 0; j < 4; ++j)
                    acc[i][j] = __builtin_amdgcn_mfma_f32_16x16x32_bf16(av[i], bv[j], acc[i][j], 0, 0, 0);
        }
        __syncthreads();
    }

    const int ccol  = lane & 15;
    const int crow4 = (lane >> 4) * 4;
#pragma unroll
    for (int i = 0; i < 4; ++i) {
#pragma unroll
        for (int j = 0; j < 4; ++j) {
#pragma unroll
            for (int r2 = 0; r2 < 4; ++r2) {
                size_t gr = bm + wm * 64 + i * 16 + crow4 + r2;
                size_t gc = bn + wn * 64 + j * 16 + ccol;
                if (gr < (size_t)Mout && gc < (size_t)Nout) {
                    float v = acc[i][j][r2];
                    if constexpr (BIAS) v += bias[gc];
                    if constexpr (RELU) v = fmaxf(v, 0.f);
                    if constexpr (OUTF32) ((float*)Cout)[gr * ldc + gc] = v;
                    else                  ((u16*)Cout)[gr * ldc + gc] = f2bf(v);
                }
            }
        }
    }
}

// ---------------- GCN aggregation: block-flat subgroups, 16B loads, 2x unroll ----------------

template <int NFEAT>
__global__ __launch_bounds__(256) void agg2_k(
    const u16* __restrict__ xw, const int* __restrict__ rowptr,
    const int* __restrict__ eidx, const float* __restrict__ ecoef,
    const float* __restrict__ dinv, const float* __restrict__ bias,
    u16* __restrict__ out, int n) {
    constexpr int LPN = NFEAT / 8;          // lanes per node (32/24/16)
    constexpr int NPB = 256 / LPN;          // nodes per block (8/10/16)
    const int tid = threadIdx.x;
    const int sub = tid / LPN;
    const int fl  = tid - sub * LPN;
    if (sub >= NPB) return;
    int node = blockIdx.x * NPB + sub;
    if (node >= n) return;

    const uint4* xv = (const uint4*)xw;
    float di = dinv[node];
    float s = di * di;
    float4 b0 = ((const float4*)bias)[fl * 2];
    float4 b1 = ((const float4*)bias)[fl * 2 + 1];
    uint4 a = xv[(size_t)node * LPN + fl];
    float acc[8];
    acc[0] = b0.x + s * bf_lo(a.x); acc[1] = b0.y + s * bf_hi(a.x);
    acc[2] = b0.z + s * bf_lo(a.y); acc[3] = b0.w + s * bf_hi(a.y);
    acc[4] = b1.x + s * bf_lo(a.z); acc[5] = b1.y + s * bf_hi(a.z);
    acc[6] = b1.z + s * bf_lo(a.w); acc[7] = b1.w + s * bf_hi(a.w);

    int beg = rowptr[node], end = rowptr[node + 1];
    int e = beg;
    for (; e + 1 < end; e += 2) {
        int sn0 = eidx[e], sn1 = eidx[e + 1];
        float c0 = ecoef[e], c1 = ecoef[e + 1];
        uint4 v0 = xv[(size_t)sn0 * LPN + fl];
        uint4 v1 = xv[(size_t)sn1 * LPN + fl];
        acc[0] = fmaf(c0, bf_lo(v0.x), acc[0]); acc[1] = fmaf(c0, bf_hi(v0.x), acc[1]);
        acc[2] = fmaf(c0, bf_lo(v0.y), acc[2]); acc[3] = fmaf(c0, bf_hi(v0.y), acc[3]);
        acc[4] = fmaf(c0, bf_lo(v0.z), acc[4]); acc[5] = fmaf(c0, bf_hi(v0.z), acc[5]);
        acc[6] = fmaf(c0, bf_lo(v0.w), acc[6]); acc[7] = fmaf(c0, bf_hi(v0.w), acc[7]);
        acc[0] = fmaf(c1, bf_lo(v1.x), acc[0]); acc[1] = fmaf(c1, bf_hi(v1.x), acc[1]);
        acc[2] = fmaf(c1, bf_lo(v1.y), acc[2]); acc[3] = fmaf(c1, bf_hi(v1.y), acc[3]);
        acc[4] = fmaf(c1, bf_lo(v1.z), acc[4]); acc[5] = fmaf(c1, bf_hi(v1.z), acc[5]);
        acc[6] = fmaf(c1, bf_lo(v1.w), acc[6]); acc[7] = fmaf(c1, bf_hi(v1.w), acc[7]);
    }
    if (e < end) {
        int sn = eidx[e];
        float c = ecoef[e];
        uint4 v = xv[(size_t)sn * LPN + fl];
        acc[0] = fmaf(c, bf_lo(v.x), acc[0]); acc[1] = fmaf(c, bf_hi(v.x), acc[1]);
        acc[2] = fmaf(c, bf_lo(v.y), acc[2]); acc[3] = fmaf(c, bf_hi(v.y), acc[3]);
        acc[4] = fmaf(c, bf_lo(v.z), acc[4]); acc[5] = fmaf(c, bf_hi(v.z), acc[5]);
        acc[6] = fmaf(c, bf_lo(v.w), acc[6]); acc[7] = fmaf(c, bf_hi(v.w), acc[7]);
    }
    uint4 o;
    o.x = (unsigned)f2bf(acc[0]) | ((unsigned)f2bf(acc[1]) << 16);
    o.y = (unsigned)f2bf(acc[2]) | ((unsigned)f2bf(acc[3]) << 16);
    o.z = (unsigned)f2bf(acc[4]) | ((unsigned)f2bf(acc[5]) << 16);
    o.w = (unsigned)f2bf(acc[6]) | ((unsigned)f2bf(acc[7]) << 16);
    ((uint4*)out)[(size_t)node * LPN + fl] = o;
}

// ---------------- launcher ----------------

extern "C" void kernel_launch(void* const* d_in, const int* in_sizes, int n_in,
                              void* d_out, int out_size, void* d_ws, size_t ws_size,
                              hipStream_t stream) {
    const float* nodes  = (const float*)d_in[0];
    const int*   edges  = (const int*)d_in[1];
    const float* labelm = (const float*)d_in[2];
    const float* W1 = (const float*)d_in[3];
    const float* b1 = (const float*)d_in[4];
    const float* W2 = (const float*)d_in[5];
    const float* b2 = (const float*)d_in[6];
    const float* W3 = (const float*)d_in[7];
    const float* b3 = (const float*)d_in[8];
    const float* fc1_w = (const float*)d_in[9];
    const float* fc1_b = (const float*)d_in[10];
    const float* fc2_w = (const float*)d_in[11];
    const float* fc2_b = (const float*)d_in[12];
    float* out = (float*)d_out;

    const int DIM = 512, N1 = 256, N2 = 192, N3 = 128, NC = 1000;
    const int n  = in_sizes[0] / DIM;   // 50000
    const int nE = in_sizes[1] / 2;     // 800000
    const int Mpad = 50048;             // 391 * 128
    const int* src = edges;
    const int* dst = edges + nE;

    // d_out scratch (200MB): dead before preds writes
    u16* P = (u16*)((char*)d_out + 67108864);      // 25.6MB
    u16* R = (u16*)((char*)d_out + 100000000);     // 12.8MB

    // ws layout
    char* ws = (char*)d_ws;
    u16*   Q      = (u16*)(ws);                  // 25,624,576
    u16*   Bt1    = (u16*)(ws + 25624576);       // 262,144
    u16*   Bt2    = (u16*)(ws + 25886720);       // 131,072
    u16*   Bt3    = (u16*)(ws + 26017792);       // 49,152
    u16*   Bfc1   = (u16*)(ws + 26066944);       // 32,768
    u16*   Wc     = (u16*)(ws + 26099712);       // 262,144
    float* bc     = (float*)(ws + 26361856);     // 4,096
    int*   deg_i  = (int*)(ws + 26365952);       // 200,000
    float* dinv   = (float*)(ws + 26565952);     // 200,000
    int*   rowptr = (int*)(ws + 26765952);       // 200,064
    int*   fill   = (int*)(ws + 26966016);       // 200,000
    int*   scanned= (int*)(ws + 27166016);       // 200,000
    int*   bsums  = (int*)(ws + 27366016);       // 256
    int*   eidx   = (int*)(ws + 27366272);       // 3,200,000
    float* ecoef  = (float*)(ws + 30566272);     // 3,200,000 (end 33.77MB)

    zero2_k<<<(n + 255) / 256, 256, 0, stream>>>(deg_i, fill, n);
    hist_k<<<(nE + 255) / 256, 256, 0, stream>>>(dst, deg_i, nE);
    int nb = (n + 1023) / 1024;
    scan_block_k<<<nb, 1024, 0, stream>>>(deg_i, scanned, bsums, n);
    scan_sums_k<<<1, 64, 0, stream>>>(bsums, nb);
    scan_final_dinv_k<<<(n + 255) / 256, 256, 0, stream>>>(scanned, deg_i, bsums, rowptr, dinv, n, nE);
    csr_fill_k<<<(nE + 255) / 256, 256, 0, stream>>>(src, dst, rowptr, fill, dinv, eidx, ecoef, nE);

    prepw_all_k<<<928, 256, 0, stream>>>(W1, Bt1, W2, Bt2, W3, Bt3, fc1_w, Bfc1);
    fuse_fc2_k<<<128, 128, 0, stream>>>(fc2_w, fc2_b, labelm, Wc, bc);

    const int gx = Mpad / 128;  // 391
    dim3 blk(256);

    // layer 1: nodes(f32, fused cast) -> P -> Q
    gemm_mfma<true, false, false, false><<<gx * 2, blk, 0, stream>>>(nodes, Bt1, nullptr, P, 512, N1, N1, Mpad, 1, n);
    agg2_k<256><<<(n + 7) / 8, blk, 0, stream>>>(P, rowptr, eidx, ecoef, dinv, b1, Q, n);
    // layer 2: Q -> P -> Q
    gemm_mfma<false, false, false, false><<<gx * 2, blk, 0, stream>>>(Q, Bt2, nullptr, P, 256, N2, N2, Mpad, 1, Mpad);
    agg2_k<192><<<(n + 9) / 10, blk, 0, stream>>>(P, rowptr, eidx, ecoef, dinv, b2, Q, n);
    // layer 3: Q -> P -> R
    gemm_mfma<false, false, false, false><<<gx, blk, 0, stream>>>(Q, Bt3, nullptr, P, 192, N3, N3, Mpad, 0, Mpad);
    agg2_k<128><<<(n + 15) / 16, blk, 0, stream>>>(P, rowptr, eidx, ecoef, dinv, b3, R, n);
    // fc1 (+relu): R -> Q
    gemm_mfma<false, false, true, true><<<gx, blk, 0, stream>>>(R, Bfc1, fc1_b, Q, 128, N3, N3, Mpad, 0, Mpad);
    // preds (fc2 folded): Q -> out
    gemm_mfma<false, true, true, false><<<gx * 8, blk, 0, stream>>>(Q, Wc, bc, out, 128, NC, NC, n, 3, Mpad);
}